// Round 6
// baseline (392.616 us; speedup 1.0000x reference)
//
#include <hip/hip_runtime.h>
#include <stdint.h>

#define Bdim 32
#define Cdim 512
#define Ndim 4096
#define Kdim 32
#define NPX 16          // pixels per chunk
#define NCH 16          // chunks per block (256 px window)
#define PWIN 16         // px-windows per image; grid k1 = Bdim*PWIN = 512

// ws: part[512][K][C] f32 (32 MiB) | wsum_part[512][K] | c2[K]
static constexpr size_t WS_WSUM_OFF = (size_t)512 * Kdim * Cdim * 4;          // 33554432
static constexpr size_t WS_C2_OFF   = WS_WSUM_OFF + (size_t)512 * Kdim * 4;   // +65536

using bf16x8 = __attribute__((ext_vector_type(8))) short;
using f32x4  = __attribute__((ext_vector_type(4))) float;

static __device__ __forceinline__ unsigned short f2bf(float f) {
    unsigned int u = __float_as_uint(f);
    u += 0x7fffu + ((u >> 16) & 1u);
    return (unsigned short)(u >> 16);
}

// ---------------------------------------------------------------------------
// K0: c2[k] = sum_c cw[k][c]^2
// ---------------------------------------------------------------------------
__global__ __launch_bounds__(256) void k0_c2(const float* __restrict__ cw,
                                             float* __restrict__ c2) {
    __shared__ float partl[8][32];
    int t = threadIdx.x;
    int k = t & 31, g = t >> 5;
    float s = 0.f;
    int c0 = g * 64;
    for (int c = c0; c < c0 + 64; ++c) {
        float v = cw[k * Cdim + c];
        s += v * v;
    }
    partl[g][k] = s;
    __syncthreads();
    if (t < 32) {
        float tot = 0.f;
        #pragma unroll
        for (int gg = 0; gg < 8; ++gg) tot += partl[gg][t];
        c2[t] = tot;
    }
}

// ---------------------------------------------------------------------------
// K1: fused. 512 blocks x 256 threads, LDS ~65 KB -> 2 blocks/CU.
// 16-px chunks; pass2 every 2 chunks (K=32 px) with 16x16x32 MFMA.
// cw pass-1 B-fragments live in registers (no cw LDS).
// ---------------------------------------------------------------------------
__global__ __launch_bounds__(256, 2) void k1_fused(const float* __restrict__ x,
                                                   const float* __restrict__ cw,
                                                   const float* __restrict__ scale,
                                                   const float* __restrict__ c2g,
                                                   float* __restrict__ part,
                                                   float* __restrict__ wsum_part) {
    __shared__ unsigned short x_n[NPX][520];     // [px16][c] bf16, pass1-A   16640 B
    __shared__ unsigned short x_t[Cdim][40];     // [c][px32] bf16, pass2-B   40960 B
    __shared__ float          S_s[2][NPX][36];   // dots, c-halves             4608 B
    __shared__ unsigned short w_t[Kdim][40];     // [k][px32] bf16, pass2-A    2560 B
    __shared__ float          x2_w[4][NPX];      //                             256 B
    __shared__ float          wsum_w[2][Kdim];   //                             256 B

    const int t    = threadIdx.x;
    const int blk  = blockIdx.x;
    const int b    = blk >> 4;
    const int pw   = blk & 15;
    const int lane = t & 63;
    const int lr   = lane & 15;
    const int lq   = lane >> 4;
    const int wv   = t >> 6;        // wave 0..3
    // staging ids
    const int pp   = t & 7;         // px pair: px = 2pp, 2pp+1 (0..15)
    const int crg  = t >> 3;        // 0..31 -> c rows {2crg+64i, +1}
    // softmax ids (t < 128)
    const int q    = t & 7;         // k-quad
    const int px   = t >> 3;        // 0..15
    // pass-1 wave roles
    const int kt2  = wv & 1;        // k half
    const int ch   = wv >> 1;       // c half

    // ---- pass-1 B-fragments (cw) -> registers, one-time (L2-cached) ----
    bf16x8 cwf[8];
    {
        const float* cr = cw + (size_t)(16 * kt2 + lr) * Cdim + 256 * ch + 8 * lq;
        #pragma unroll
        for (int s = 0; s < 8; ++s) {
            float4 v0 = *(const float4*)(cr + 32 * s);
            float4 v1 = *(const float4*)(cr + 32 * s + 4);
            bf16x8 f;
            f[0] = (short)f2bf(v0.x); f[1] = (short)f2bf(v0.y);
            f[2] = (short)f2bf(v0.z); f[3] = (short)f2bf(v0.w);
            f[4] = (short)f2bf(v1.x); f[5] = (short)f2bf(v1.y);
            f[6] = (short)f2bf(v1.z); f[7] = (short)f2bf(v1.w);
            cwf[s] = f;
        }
    }

    float4 sc4, c24;
    if (t < 128) {
        sc4 = *(const float4*)(scale + 4 * q);
        c24 = *(const float4*)(c2g + 4 * q);
    }

    const float* xb = x + (size_t)b * Cdim * Ndim + pw * (NPX * NCH);

    // prefetch chunk 0
    float2 pa[8], pb[8];
    #pragma unroll
    for (int i = 0; i < 8; ++i) {
        int c = 2 * crg + 64 * i;
        pa[i] = *(const float2*)(xb + (size_t)c * Ndim + 2 * pp);
        pb[i] = *(const float2*)(xb + (size_t)(c + 1) * Ndim + 2 * pp);
    }

    f32x4 acc[2][8];                 // [k-half][c-tile]; wave owns 128 c
    #pragma unroll
    for (int kt = 0; kt < 2; ++kt)
        #pragma unroll
        for (int ct = 0; ct < 8; ++ct) acc[kt][ct] = (f32x4){0.f, 0.f, 0.f, 0.f};
    float wsum_r[4] = {0.f, 0.f, 0.f, 0.f};   // t<128

    for (int ci = 0; ci < NCH; ++ci) {
        const int par = (ci & 1) * NPX;   // px-half slot in x_t / w_t

        // ---------------- stage from prefetch regs ----------------
        float x2p0 = 0.f, x2p1 = 0.f;
        #pragma unroll
        for (int i = 0; i < 8; ++i) {
            int c = 2 * crg + 64 * i;
            float2 a = pa[i], bb = pb[i];
            unsigned short ax = f2bf(a.x), ay = f2bf(a.y);
            unsigned short bx = f2bf(bb.x), by = f2bf(bb.y);
            ushort2 u;
            u.x = ax; u.y = ay; *(ushort2*)&x_t[c][par + 2 * pp] = u;
            u.x = bx; u.y = by; *(ushort2*)&x_t[c + 1][par + 2 * pp] = u;
            u.x = ax; u.y = bx; *(ushort2*)&x_n[2 * pp][c] = u;
            u.x = ay; u.y = by; *(ushort2*)&x_n[2 * pp + 1][c] = u;
            x2p0 += a.x * a.x + bb.x * bb.x;
            x2p1 += a.y * a.y + bb.y * bb.y;
        }
        x2p0 += __shfl_xor(x2p0, 8);  x2p1 += __shfl_xor(x2p1, 8);
        x2p0 += __shfl_xor(x2p0, 16); x2p1 += __shfl_xor(x2p1, 16);
        x2p0 += __shfl_xor(x2p0, 32); x2p1 += __shfl_xor(x2p1, 32);
        if (lane < 8) {
            float2 v; v.x = x2p0; v.y = x2p1;
            *(float2*)&x2_w[wv][2 * pp] = v;
        }
        __syncthreads();   // B1

        // prefetch next chunk inside pass-1 phase (drain lands at B2,
        // partially covered by MFMA; cross-block overlap covers the rest)
        if (ci + 1 < NCH) {
            const float* xn2 = xb + (ci + 1) * NPX;
            #pragma unroll
            for (int i = 0; i < 8; ++i) {
                int c = 2 * crg + 64 * i;
                pa[i] = *(const float2*)(xn2 + (size_t)c * Ndim + 2 * pp);
                pb[i] = *(const float2*)(xn2 + (size_t)(c + 1) * Ndim + 2 * pp);
            }
        }

        // ---------------- pass 1: dots via MFMA ----------------
        {
            f32x4 d = (f32x4){0.f, 0.f, 0.f, 0.f};
            #pragma unroll
            for (int s = 0; s < 8; ++s) {
                bf16x8 av = *(const bf16x8*)&x_n[lr][256 * ch + 32 * s + 8 * lq];
                d = __builtin_amdgcn_mfma_f32_16x16x32_bf16(av, cwf[s], d, 0, 0, 0);
            }
            #pragma unroll
            for (int r = 0; r < 4; ++r)
                S_s[ch][4 * lq + r][16 * kt2 + lr] = d[r];
        }
        __syncthreads();   // B2

        // ---------------- softmax (t<128: px, k-quad q) ----------------
        if (t < 128) {
            float4 dv0 = *(const float4*)&S_s[0][px][4 * q];
            float4 dv1 = *(const float4*)&S_s[1][px][4 * q];
            float xx = x2_w[0][px] + x2_w[1][px] + x2_w[2][px] + x2_w[3][px];
            float d0 = sc4.x * (xx - 2.f * (dv0.x + dv1.x) + c24.x);
            float d1 = sc4.y * (xx - 2.f * (dv0.y + dv1.y) + c24.y);
            float d2 = sc4.z * (xx - 2.f * (dv0.z + dv1.z) + c24.z);
            float d3 = sc4.w * (xx - 2.f * (dv0.w + dv1.w) + c24.w);
            float m = fmaxf(fmaxf(d0, d1), fmaxf(d2, d3));
            m = fmaxf(m, __shfl_xor(m, 1));
            m = fmaxf(m, __shfl_xor(m, 2));
            m = fmaxf(m, __shfl_xor(m, 4));
            float e0 = __expf(d0 - m), e1 = __expf(d1 - m);
            float e2 = __expf(d2 - m), e3 = __expf(d3 - m);
            float ss = e0 + e1 + e2 + e3;
            ss += __shfl_xor(ss, 1);
            ss += __shfl_xor(ss, 2);
            ss += __shfl_xor(ss, 4);
            float inv = 1.f / ss;
            float w0 = e0 * inv, w1 = e1 * inv, w2 = e2 * inv, w3 = e3 * inv;
            wsum_r[0] += w0; wsum_r[1] += w1; wsum_r[2] += w2; wsum_r[3] += w3;
            w_t[4 * q + 0][par + px] = f2bf(w0);
            w_t[4 * q + 1][par + px] = f2bf(w1);
            w_t[4 * q + 2][par + px] = f2bf(w2);
            w_t[4 * q + 3][par + px] = f2bf(w3);
        }
        __syncthreads();   // B3

        // ---------------- pass 2 every 2 chunks (K = 32 px) ----------------
        if (ci & 1) {
            bf16x8 a0 = *(const bf16x8*)&w_t[lr][8 * lq];
            bf16x8 a1 = *(const bf16x8*)&w_t[16 + lr][8 * lq];
            #pragma unroll
            for (int ct = 0; ct < 8; ++ct) {
                bf16x8 bv = *(const bf16x8*)&x_t[128 * wv + 16 * ct + lr][8 * lq];
                acc[0][ct] = __builtin_amdgcn_mfma_f32_16x16x32_bf16(a0, bv, acc[0][ct], 0, 0, 0);
                acc[1][ct] = __builtin_amdgcn_mfma_f32_16x16x32_bf16(a1, bv, acc[1][ct], 0, 0, 0);
            }
            __syncthreads();   // B4: x_t/w_t consumed before next stage
        }
    }

    // ---------------- epilogue ----------------
    if (t < 128) {
        #pragma unroll
        for (int j = 0; j < 4; ++j) {
            float v = wsum_r[j];
            v += __shfl_xor(v, 8);
            v += __shfl_xor(v, 16);
            v += __shfl_xor(v, 32);
            if (lane < 8) wsum_w[wv][4 * lane + j] = v;
        }
    }
    {
        float* pbuf = part + (size_t)blk * (Kdim * Cdim);
        #pragma unroll
        for (int kt = 0; kt < 2; ++kt)
            #pragma unroll
            for (int ct = 0; ct < 8; ++ct)
                #pragma unroll
                for (int r = 0; r < 4; ++r)
                    pbuf[(size_t)(16 * kt + 4 * lq + r) * Cdim + 128 * wv + 16 * ct + lr] =
                        acc[kt][ct][r];
    }
    __syncthreads();
    if (t < 32) wsum_part[blk * Kdim + t] = wsum_w[0][t] + wsum_w[1][t];
}

// ---------------------------------------------------------------------------
// K2: reduce 16 partials per (b,k) + subtract wsum*cw.
// ---------------------------------------------------------------------------
__global__ __launch_bounds__(256) void k2_reduce(const float* __restrict__ part,
                                                 const float* __restrict__ wsum_part,
                                                 const float* __restrict__ cw,
                                                 float* __restrict__ out) {
    int blk = blockIdx.x;
    int b = blk >> 5, k = blk & 31;
    int t = threadIdx.x;
    float ws = 0.f;
    #pragma unroll
    for (int p = 0; p < PWIN; ++p) ws += wsum_part[(b * PWIN + p) * Kdim + k];
    int c = 2 * t;
    float sx = 0.f, sy = 0.f;
    #pragma unroll
    for (int p = 0; p < PWIN; ++p) {
        const float2 v = *(const float2*)(part + ((size_t)(b * PWIN + p) * Kdim + k) * Cdim + c);
        sx += v.x;
        sy += v.y;
    }
    float2 cv = *(const float2*)(cw + (size_t)k * Cdim + c);
    float2 o;
    o.x = sx - ws * cv.x;
    o.y = sy - ws * cv.y;
    *(float2*)(out + ((size_t)b * Kdim + k) * Cdim + c) = o;
}

// ---------------------------------------------------------------------------
extern "C" void kernel_launch(void* const* d_in, const int* in_sizes, int n_in,
                              void* d_out, int out_size, void* d_ws, size_t ws_size,
                              hipStream_t stream) {
    const float* x     = (const float*)d_in[0];   // [B][C][N]
    const float* cw    = (const float*)d_in[1];   // [K][C]
    const float* scale = (const float*)d_in[2];   // [K]
    float* out = (float*)d_out;                   // [B][K][C]

    char* wsb = (char*)d_ws;
    float* part      = (float*)wsb;
    float* wsum_part = (float*)(wsb + WS_WSUM_OFF);
    float* c2        = (float*)(wsb + WS_C2_OFF);

    k0_c2<<<1, 256, 0, stream>>>(cw, c2);
    k1_fused<<<Bdim * PWIN, 256, 0, stream>>>(x, cw, scale, c2, part, wsum_part);
    k2_reduce<<<Bdim * Kdim, 256, 0, stream>>>(part, wsum_part, cw, out);
}